// Round 2
// baseline (43989.990 us; speedup 1.0000x reference)
//
#include <hip/hip_runtime.h>

// B=64, T=256, H=1024, L=6. x and weight_ih are dead on this path.
// Cell: h_new = tanh((prev + h_old) @ Whh^T + bias_ih + bias_bh)
// 1536 fully-sequential cells; batch elements independent -> one persistent
// workgroup per batch element, zero inter-block sync. W streamed from L2 as
// fp32 in a transposed float4 layout (exact fp32 math: round-1 fp16 version
// failed h_final at 2.6e-2 vs 1.9e-2 threshold from quantization noise).

#define BB 64
#define TT 256
#define HH 1024
#define LL 6

// Repack W into float4-transposed layout: Wp[kk][j][i] = W[j][4*kk+i]
// Main kernel reads Wp4[(kk<<10)|j] -> lanes consecutive in j => 1KB/wave
// contiguous, 16B/lane.
__global__ void prep_kernel(const float* __restrict__ Whh,
                            const float* __restrict__ bias_ih,
                            const float* __restrict__ bias_bh,
                            float4* __restrict__ Wp,
                            float* __restrict__ bias_sum) {
    int tid = blockIdx.x * blockDim.x + threadIdx.x;   // 0 .. 262143
    int j   = tid & (HH - 1);
    int kk  = tid >> 10;                               // 0..255
    const float* src = Whh + (size_t)j * HH + (kk << 2);
    Wp[tid] = make_float4(src[0], src[1], src[2], src[3]);
    if (tid < HH) bias_sum[tid] = bias_ih[tid] + bias_bh[tid];
}

__global__ void __launch_bounds__(1024, 1)
rnn_kernel(const float* __restrict__ h0,
           const float4* __restrict__ Wp,       // [256][1024] float4
           const float* __restrict__ bias_sum,
           const float* __restrict__ w_out,
           const float* __restrict__ b_out,
           float* __restrict__ d_out) {
    __shared__ float h_lds[LL][HH];   // 24 KB  hidden state
    __shared__ float s_lds[HH];       //  4 KB  s = prev + h_old (f32, exact)
    __shared__ float prev[HH];        //  4 KB  chained activation
    __shared__ float wout_s[HH];
    __shared__ float red[16];

    const int b = blockIdx.x;
    const int j = threadIdx.x;

#pragma unroll
    for (int l = 0; l < LL; ++l) h_lds[l][j] = h0[((size_t)(l * BB) + b) * HH + j];
    prev[j]   = h_lds[LL - 1][j];
    wout_s[j] = w_out[j];
    const float bj = bias_sum[j];
    const float bo = b_out[0];
    __syncthreads();

    const float4* s4 = (const float4*)s_lds;

    for (int t = 0; t < TT; ++t) {
        for (int l = 0; l < LL; ++l) {
            s_lds[j] = prev[j] + h_lds[l][j];
            __syncthreads();   // s ready; all reads of prev/h_lds[l] done

            float acc = 0.f;
#pragma unroll 8
            for (int kk = 0; kk < HH / 4; ++kk) {
                float4 w = Wp[(kk << 10) | j];  // 16B/lane coalesced L2 stream
                float4 x = s4[kk];              // wave-uniform LDS broadcast
                acc = fmaf(w.x, x.x, acc);
                acc = fmaf(w.y, x.y, acc);
                acc = fmaf(w.z, x.z, acc);
                acc = fmaf(w.w, x.w, acc);
            }
            float y = tanhf(acc + bj);

            h_lds[l][j] = y;   // safe: s_lds holds the consumed sum
            prev[j]     = y;

            if (l == LL - 1) {
                float c = y * wout_s[j];
#pragma unroll
                for (int off = 32; off; off >>= 1) c += __shfl_down(c, off, 64);
                if ((j & 63) == 0) red[j >> 6] = c;
            }
            __syncthreads();   // publish h_lds/prev (and red) for next cell

            if (l == LL - 1 && j == 0) {
                float s = bo;
#pragma unroll
                for (int w = 0; w < 16; ++w) s += red[w];
                d_out[b * TT + t] = s;   // out[b, t, 0]
            }
        }
    }

    // h_final: [L, B, H] at offset B*T
#pragma unroll
    for (int l = 0; l < LL; ++l)
        d_out[BB * TT + ((size_t)(l * BB + b) << 10) + j] = h_lds[l][j];
}

extern "C" void kernel_launch(void* const* d_in, const int* in_sizes, int n_in,
                              void* d_out, int out_size, void* d_ws, size_t ws_size,
                              hipStream_t stream) {
    // inputs: 0:x(unused) 1:h0 2:weight_ih(unused) 3:bias_ih 4:weight_hh 5:bias_bh 6:w_out 7:b_out
    const float* h0      = (const float*)d_in[1];
    const float* bias_ih = (const float*)d_in[3];
    const float* Whh     = (const float*)d_in[4];
    const float* bias_bh = (const float*)d_in[5];
    const float* w_out   = (const float*)d_in[6];
    const float* b_out   = (const float*)d_in[7];

    float4* Wp      = (float4*)d_ws;                                    // 4 MB
    float* bias_sum = (float*)((char*)d_ws + (size_t)HH * HH * 4);      // 4 KB

    prep_kernel<<<1024, 256, 0, stream>>>(Whh, bias_ih, bias_bh, Wp, bias_sum);
    rnn_kernel<<<BB, 1024, 0, stream>>>(h0, Wp, bias_sum,
                                        w_out, b_out, (float*)d_out);
}

// Round 4
// 22170.166 us; speedup vs baseline: 1.9842x; 1.9842x over previous
//
#include <hip/hip_runtime.h>

// B=64, T=256, H=1024, L=6. Cell: h = tanh((prev + h_old) @ W^T + b1 + b2).
// W resident in LDS across 256 CUs: 8 groups (8 batches each) x 32 j-slice
// blocks. Per-cell 32-block barrier via agent-scope atomics, fresh flag slot
// per cell (memset each launch -> replay/graph-safe). Hidden state parity
// double-buffered in global (L2-resident).
// Round-3 bug: partial[] stride was NG(8) but q spans NQ(32) -> output-0
// corruption. Fixed: stride NQ, sum over all 32 slice partials.

#define BB 64
#define TT 256
#define HH 1024
#define LL 6
#define NG 8     // groups, GB batches each
#define GB 8     // batches per group
#define NQ 32    // blocks (j-slices) per group
#define SJ 32    // j rows per block
#define NTH 256

#define HSTATE_FLOATS (2ull * BB * LL * HH)            // parity x b x l x k
#define FLAGS_OFF   (HSTATE_FLOATS * 4)                // 3,145,728 B
#define NSLOTS      (1 + TT * LL)                      // 1537 barriers
#define FLAG_STRIDE 16                                 // 64B per (slot,group)
#define FLAGS_BYTES ((size_t)NSLOTS * NG * FLAG_STRIDE * 4)
#define PARTIAL_OFF (FLAGS_OFF + FLAGS_BYTES)          // [2][BB][NQ] floats

__global__ void __launch_bounds__(NTH, 1)
rnn_kernel(const float* __restrict__ h0,
           const float* __restrict__ Whh,
           const float* __restrict__ bias_ih,
           const float* __restrict__ bias_bh,
           const float* __restrict__ w_out,
           const float* __restrict__ b_out,
           float* hstate, unsigned* flags, float* partial,
           float* __restrict__ d_out)
{
    __shared__ float4 Wl4[256 * SJ];   // [k4][j_local], 128 KB: W[j][4k..4k+3]
    __shared__ float4 s4[GB * 64];     // one 256-k chunk of s: [b_local][k4], 8 KB

    const int tid = threadIdx.x;
    const int g   = blockIdx.x & 7;    // group
    const int q   = blockIdx.x >> 3;   // j-slice index 0..31
    const int gb  = g * GB;
    const int jl  = tid & 31;
    const int bl  = tid >> 5;
    const int jg  = q * SJ + jl;
    const int b   = gb + bl;

    // ---- W slice -> LDS (once). global coalesced along k; layout [k4][jl].
    for (int it = 0; it < 32; ++it) {
        int idx  = it * NTH + tid;     // = jrow*256 + k4
        int jrow = idx >> 8;
        int k4   = idx & 255;
        const float4* src = (const float4*)(Whh + (size_t)(q * SJ + jrow) * HH);
        Wl4[k4 * SJ + jrow] = src[k4];
    }

    const float bias_j = bias_ih[jg] + bias_bh[jg];
    const float wout_j = w_out[jg];
    const float bout   = b_out[0];

    // ---- init hstate parity 1 from h0 ([l*BB+b][k] layout)
    for (int l = 0; l < LL; ++l)
        hstate[(((size_t)1 * BB + b) * LL + l) * HH + jg] =
            h0[((size_t)l * BB + b) * HH + jg];

    auto gbar = [&](int slot) {
        __syncthreads();
        if (tid == 0) {
            unsigned* f = flags + ((size_t)slot * NG + g) * FLAG_STRIDE;
            __hip_atomic_fetch_add(f, 1u, __ATOMIC_RELEASE, __HIP_MEMORY_SCOPE_AGENT);
            for (int w = 0; w < 50000; ++w) {   // bounded: no hang if non-resident
                if (__hip_atomic_load(f, __ATOMIC_ACQUIRE, __HIP_MEMORY_SCOPE_AGENT) >= NQ)
                    break;
                __builtin_amdgcn_s_sleep(2);
            }
        }
        __syncthreads();
    };

    gbar(0);   // publish init

    for (int t = 0; t < TT; ++t) {
        const int pw = t & 1, pr = pw ^ 1;
        for (int l = 0; l < LL; ++l) {
            const int lp = (l == 0) ? (LL - 1) : (l - 1);
            const int pp = (l == 0) ? pr : pw;   // prev-chain parity

            float acc = 0.f;
            for (int ch = 0; ch < 4; ++ch) {
                // cooperative load of s-chunk: s = prev + h_old, 8b x 256k
#pragma unroll
                for (int r = 0; r < 2; ++r) {
                    int idx = tid + r * NTH;        // [0,512): bb*64 + kk
                    int bb = idx >> 6, kk = idx & 63;
                    const float4* P  = (const float4*)(hstate +
                        (((size_t)pp * BB + gb + bb) * LL + lp) * HH + ch * 256);
                    const float4* Ho = (const float4*)(hstate +
                        (((size_t)pr * BB + gb + bb) * LL + l) * HH + ch * 256);
                    float4 a = P[kk], c = Ho[kk];
                    s4[idx] = make_float4(a.x + c.x, a.y + c.y, a.z + c.z, a.w + c.w);
                }
                __syncthreads();

                const float4* wbase = Wl4 + (size_t)ch * 64 * SJ;
#pragma unroll 8
                for (int kk = 0; kk < 64; ++kk) {
                    float4 w = wbase[kk * SJ + jl];   // consecutive lanes: conflict-free
                    float4 x = s4[bl * 64 + kk];      // broadcast (2 addrs/wave)
                    acc = fmaf(w.x, x.x, fmaf(w.y, x.y,
                          fmaf(w.z, x.z, fmaf(w.w, x.w, acc))));
                }
                __syncthreads();
            }

            float y = tanhf(acc + bias_j);
            hstate[(((size_t)pw * BB + b) * LL + l) * HH + jg] = y;

            if (l == LL - 1) {
                float c = y * wout_j;
#pragma unroll
                for (int off = 16; off; off >>= 1) c += __shfl_down(c, off, 32);
                if ((tid & 31) == 0)
                    partial[(size_t)pw * BB * NQ + (size_t)b * NQ + q] = c;
            }
            if (t == TT - 1)
                d_out[(size_t)BB * TT + ((size_t)l * BB + b) * HH + jg] = y;

            gbar(1 + t * LL + l);

            if (l == LL - 1 && q == 0 && tid < GB) {
                int bo = gb + tid;
                float s = bout;
#pragma unroll
                for (int qq = 0; qq < NQ; ++qq)
                    s += partial[(size_t)pw * BB * NQ + (size_t)bo * NQ + qq];
                d_out[(size_t)bo * TT + t] = s;    // out[b, t, 0]
            }
        }
    }
}

extern "C" void kernel_launch(void* const* d_in, const int* in_sizes, int n_in,
                              void* d_out, int out_size, void* d_ws, size_t ws_size,
                              hipStream_t stream) {
    // inputs: 0:x(unused) 1:h0 2:weight_ih(unused) 3:bias_ih 4:weight_hh 5:bias_bh 6:w_out 7:b_out
    const float* h0      = (const float*)d_in[1];
    const float* bias_ih = (const float*)d_in[3];
    const float* Whh     = (const float*)d_in[4];
    const float* bias_bh = (const float*)d_in[5];
    const float* w_out   = (const float*)d_in[6];
    const float* b_out   = (const float*)d_in[7];

    float*    hstate  = (float*)d_ws;
    unsigned* flags   = (unsigned*)((char*)d_ws + FLAGS_OFF);
    float*    partial = (float*)((char*)d_ws + PARTIAL_OFF);

    hipMemsetAsync(flags, 0, FLAGS_BYTES, stream);   // fresh barriers every launch/replay
    rnn_kernel<<<NG * NQ, NTH, 0, stream>>>(h0, Whh, bias_ih, bias_bh,
                                            w_out, b_out, hstate, flags, partial,
                                            (float*)d_out);
}